// Round 5
// baseline (5498.522 us; speedup 1.0000x reference)
//
#include <hip/hip_runtime.h>

// Problem constants
#define TT 256
#define BB 256
#define EE 512
#define HH 1024
#define G4 4096
#define KTOT 1536
#define MB 32          // batch rows per block (8 groups of 32)
#define NBLK 512       // 64 j-tiles x 8 batch groups
#define CK 256         // K columns per staged chunk (round 2 had 128)
#define APAD 8

typedef __attribute__((ext_vector_type(8))) short short8;
typedef __attribute__((ext_vector_type(4))) float f32x4;

__device__ __forceinline__ short f2bf(float f) {
    unsigned u; __builtin_memcpy(&u, &f, 4);
    unsigned r = (u + 0x7FFFu + ((u >> 16) & 1u)) >> 16;   // RNE
    return (short)(unsigned short)r;
}
__device__ __forceinline__ float bf2f(short s) {
    unsigned u = ((unsigned)(unsigned short)s) << 16;
    float f; __builtin_memcpy(&f, &u, 4);
    return f;
}
__device__ __forceinline__ float sigf(float x) {
    return __builtin_amdgcn_rcpf(1.f + __expf(-x));
}
__device__ __forceinline__ float tanh_fast(float x) {
    return 2.f * sigf(x + x) - 1.f;
}

// Device-coherent 16-B h load: two agent-scope relaxed 8-B atomic loads
// (bypass possibly-stale L1/L2 -> fresh from L3). Proven in round 2.
__device__ __forceinline__ short8 ldh16(const short* p) {
    unsigned long long a = __hip_atomic_load((const unsigned long long*)p,
                                             __ATOMIC_RELAXED, __HIP_MEMORY_SCOPE_AGENT);
    unsigned long long b = __hip_atomic_load((const unsigned long long*)(p + 4),
                                             __ATOMIC_RELAXED, __HIP_MEMORY_SCOPE_AGENT);
    short8 v;
    __builtin_memcpy(&v, &a, 8);
    __builtin_memcpy((char*)&v + 8, &b, 8);
    return v;
}

// ---------------------------------------------------------------------------
// Prep: w_cat[r][0:1024]=w_hh[r], w_cat[r][1024:1536]=w_ih[r] (bf16);
//       bias[r] = b_ih[r] + b_hh[r]; block 0 zeroes barrier words.
// ---------------------------------------------------------------------------
__global__ __launch_bounds__(256) void prep_kernel(
    const float* __restrict__ w_ih, const float* __restrict__ w_hh,
    const float* __restrict__ b_ih, const float* __restrict__ b_hh,
    short* __restrict__ w_cat, float* __restrict__ bias,
    unsigned* __restrict__ bar)
{
    int r = blockIdx.x;
    int tid = threadIdx.x;
    for (int c = tid; c < KTOT; c += 256) {
        float v = (c < HH) ? w_hh[(size_t)r * HH + c]
                           : w_ih[(size_t)r * EE + (c - HH)];
        w_cat[(size_t)r * KTOT + c] = f2bf(v);
    }
    if (tid == 0) bias[r] = b_ih[r] + b_hh[r];
    if (r == 0) {
        for (int i = tid; i < 512; i += 256)
            __hip_atomic_store(bar + i, 0u, __ATOMIC_RELAXED, __HIP_MEMORY_SCOPE_AGENT);
    }
}

// ---------------------------------------------------------------------------
// Gather + convert: x_bf[t][b][:] = bf16(emb[text[b][t]][:])
// ---------------------------------------------------------------------------
__global__ __launch_bounds__(256) void gather_kernel(
    const int* __restrict__ text, const float* __restrict__ emb,
    short* __restrict__ xbf)
{
    int row = blockIdx.x * 4 + (threadIdx.x >> 6);   // b*TT + t
    int b = row >> 8, t = row & 255;
    int lane = threadIdx.x & 63;
    int v = text[row];
    const float* src = emb + (size_t)v * EE + lane * 8;
    float4 f0 = *(const float4*)src;
    float4 f1 = *(const float4*)(src + 4);
    float fv[8];
    *(float4*)&fv[0] = f0; *(float4*)&fv[4] = f1;
    short8 s;
    #pragma unroll
    for (int i = 0; i < 8; ++i) s[i] = f2bf(fv[i]);
    *(short8*)(xbf + ((size_t)t * BB + b) * EE + lane * 8) = s;
}

// ---------------------------------------------------------------------------
// Persistent LSTM, 512 blocks x 256 threads (2 blocks/CU).
// EXACT round-2 structure (verified pass @4092us), with the single change:
// staged chunk width 128 -> 256 columns (12 -> 6 chunks, 13 -> 8 barriers
// per step). Wave wv = gate wv; each wave computes both 16-row batch halves
// (acc0/acc1). Per-group split-phase barrier (cnt/gen) unchanged.
// ---------------------------------------------------------------------------
__global__ __launch_bounds__(256, 2) void lstm_seq(
    const short* __restrict__ w_cat,   // [4096][1536] bf16
    const float* __restrict__ bias,    // [4096]
    const short* __restrict__ xbf,     // [T][B][E] bf16
    short*       __restrict__ hbuf0,   // [B][H] bf16
    short*       __restrict__ hbuf1,   // [B][H] bf16
    unsigned*    __restrict__ bar)     // 8 groups x 64 u32 stride
{
    __shared__ short At[2][MB][CK + APAD];   // 2 x 32 x 264 bf16 = 33792 B
    __shared__ float Gt[4][MB][17];          // 8704 B   (total 42496 B)

    const int tid  = threadIdx.x;
    const int wv   = tid >> 6;               // gate 0..3 (i,f,g,o)
    const int lane = tid & 63;
    const int n    = lane & 15;
    const int q    = lane >> 4;

    const int bid = blockIdx.x;
    const int xcd = bid & 7, sub = bid >> 3;   // sub 0..63
    const int jt  = xcd * 8 + (sub & 7);       // 0..63 j-tile (XCD-swizzled)
    const int g   = sub >> 3;                  // 0..7 batch group
    const int j0  = jt * 16;
    const int b0  = g * MB;

    unsigned* cnt = bar + g * 64;
    unsigned* gen = bar + g * 64 + 16;

    const short* wrow = w_cat + (size_t)(wv * HH + j0 + n) * KTOT;

    // A staging: thread -> (row ar, cols ac..ac+31) of the 32x256 chunk
    const int ar = tid >> 3;                 // 0..31
    const int ac = (tid & 7) * 32;           // 0,32,...,224
    const int ab = b0 + ar;
    const short* hrow0 = hbuf0 + (size_t)ab * HH + ac;
    const short* hrow1 = hbuf1 + (size_t)ab * HH + ac;
    const short* xbase = xbf + (size_t)ab * EE + ac;

    // Elementwise mapping: thread owns (batch eb, j jb..jb+1)
    const int m  = tid >> 3;
    const int n2 = (tid & 7) * 2;
    const int jb = j0 + n2;
    const int eb = b0 + m;
    float bi_[2], bf_[2], bg_[2], bo_[2];
    #pragma unroll
    for (int u = 0; u < 2; ++u) {
        bi_[u] = bias[jb + u];
        bf_[u] = bias[HH + jb + u];
        bg_[u] = bias[2 * HH + jb + u];
        bo_[u] = bias[3 * HH + jb + u];
    }
    float creg[2] = {0.f, 0.f};
    unsigned* hout_e = (unsigned*)(hbuf1 + (size_t)eb * HH + jb);  // even t
    unsigned* hout_o = (unsigned*)(hbuf0 + (size_t)eb * HH + jb);  // odd t

    f32x4 acc0, acc1;

    // --- helpers (round-2 idioms, widened to 256-col chunks) ---------------
    auto stage4 = [&](int buf, short8 v0, short8 v1, short8 v2, short8 v3) {
        *(short8*)&At[buf][ar][ac]      = v0;
        *(short8*)&At[buf][ar][ac + 8]  = v1;
        *(short8*)&At[buf][ar][ac + 16] = v2;
        *(short8*)&At[buf][ar][ac + 24] = v3;
    };
    auto mfma_chunk = [&](int buf, int k0) {      // one 256-col chunk
        #pragma unroll
        for (int ks = 0; ks < 8; ++ks) {
            short8 bfrag = *(const short8*)(wrow + k0 + ks * 32 + q * 8);
            short8 a0 = *(const short8*)&At[buf][n][ks * 32 + q * 8];
            short8 a1 = *(const short8*)&At[buf][16 + n][ks * 32 + q * 8];
            acc0 = __builtin_amdgcn_mfma_f32_16x16x32_bf16(a0, bfrag, acc0, 0, 0, 0);
            acc1 = __builtin_amdgcn_mfma_f32_16x16x32_bf16(a1, bfrag, acc1, 0, 0, 0);
        }
    };

    // x-part of step t's gates (K columns 1024..1536), 2 chunks
    auto compute_x = [&](int t) {
        acc0 = (f32x4){0.f, 0.f, 0.f, 0.f};
        acc1 = (f32x4){0.f, 0.f, 0.f, 0.f};
        const short* xp = xbase + (size_t)t * (BB * EE);
        stage4(0, __builtin_nontemporal_load((const short8*)xp),
                  __builtin_nontemporal_load((const short8*)(xp + 8)),
                  __builtin_nontemporal_load((const short8*)(xp + 16)),
                  __builtin_nontemporal_load((const short8*)(xp + 24)));
        __syncthreads();
        short8 r0 = __builtin_nontemporal_load((const short8*)(xp + CK));
        short8 r1 = __builtin_nontemporal_load((const short8*)(xp + CK + 8));
        short8 r2 = __builtin_nontemporal_load((const short8*)(xp + CK + 16));
        short8 r3 = __builtin_nontemporal_load((const short8*)(xp + CK + 24));
        mfma_chunk(0, HH);
        stage4(1, r0, r1, r2, r3);
        __syncthreads();
        mfma_chunk(1, HH + CK);
    };

    // h-part of step t's gates (K columns 0..1024), 4 chunks, coherent loads
    auto compute_h = [&](int t) {
        const short* hp = (t & 1) ? hrow1 : hrow0;
        stage4(0, ldh16(hp), ldh16(hp + 8), ldh16(hp + 16), ldh16(hp + 24));
        __syncthreads();
        #pragma unroll
        for (int c = 0; c < 4; ++c) {
            short8 r0, r1, r2, r3;
            if (c < 3) {
                const short* p = hp + (c + 1) * CK;
                r0 = ldh16(p);
                r1 = ldh16(p + 8);
                r2 = ldh16(p + 16);
                r3 = ldh16(p + 24);
            }
            mfma_chunk(c & 1, c * CK);
            if (c < 3) { stage4((c & 1) ^ 1, r0, r1, r2, r3); __syncthreads(); }
        }
    };
    // -----------------------------------------------------------------------

    compute_x(0);
    for (int t = 0; t < TT; ++t) {
        if (t > 0) {
            // wait for h(t-1): gen reaches t when all 64 group blocks arrived
            if (tid == 0) {
                while (__hip_atomic_load(gen, __ATOMIC_RELAXED, __HIP_MEMORY_SCOPE_AGENT)
                       < (unsigned)t)
                    __builtin_amdgcn_s_sleep(2);
            }
            __syncthreads();
            compute_h(t);
        }

        // Gate exchange through LDS
        #pragma unroll
        for (int r = 0; r < 4; ++r) {
            Gt[wv][q * 4 + r][n]      = acc0[r];
            Gt[wv][16 + q * 4 + r][n] = acc1[r];
        }
        __syncthreads();

        // Elementwise cell update (c in registers); coherent packed h store
        unsigned hw;
        {
            unsigned short hlo, hhi;
            #pragma unroll
            for (int u = 0; u < 2; ++u) {
                float ip = Gt[0][m][n2 + u] + bi_[u];
                float fp = Gt[1][m][n2 + u] + bf_[u];
                float gp = Gt[2][m][n2 + u] + bg_[u];
                float op = Gt[3][m][n2 + u] + bo_[u];
                float cn = sigf(fp) * creg[u] + sigf(ip) * tanh_fast(gp);
                creg[u]  = cn;
                unsigned short hb = (unsigned short)f2bf(sigf(op) * tanh_fast(cn));
                if (u == 0) hlo = hb; else hhi = hb;
            }
            hw = (unsigned)hlo | ((unsigned)hhi << 16);
        }
        __hip_atomic_store((t & 1) ? hout_o : hout_e, hw,
                           __ATOMIC_RELAXED, __HIP_MEMORY_SCOPE_AGENT);

        if (t + 1 < TT) {
            __syncthreads();   // all h stores drained (vmcnt) before arrival
            if (tid == 0) {
                unsigned a = __hip_atomic_fetch_add(cnt, 1u, __ATOMIC_RELAXED,
                                                    __HIP_MEMORY_SCOPE_AGENT);
                if (a == 63u) {
                    __hip_atomic_store(cnt, 0u, __ATOMIC_RELAXED,
                                       __HIP_MEMORY_SCOPE_AGENT);
                    __hip_atomic_fetch_add(gen, 1u, __ATOMIC_RELEASE,
                                           __HIP_MEMORY_SCOPE_AGENT);
                }
            }
            compute_x(t + 1);  // hide barrier resolution behind x-part GEMM
        }
    }
}

// ---------------------------------------------------------------------------
// FC head: out[b] = sigmoid(dot(h[b], fc_w) + fc_b)
// ---------------------------------------------------------------------------
__global__ __launch_bounds__(256) void fc_kernel(
    const short* __restrict__ hbuf, const float* __restrict__ fc_w,
    const float* __restrict__ fc_b, float* __restrict__ out)
{
    __shared__ float red[4];
    int b = blockIdx.x;
    int tid = threadIdx.x;
    float s = 0.f;
    for (int k = tid; k < HH; k += 256)
        s += bf2f(hbuf[(size_t)b * HH + k]) * fc_w[k];
    #pragma unroll
    for (int off = 32; off > 0; off >>= 1) s += __shfl_down(s, off);
    if ((tid & 63) == 0) red[tid >> 6] = s;
    __syncthreads();
    if (tid == 0) {
        float tot = red[0] + red[1] + red[2] + red[3] + fc_b[0];
        out[b] = 1.f / (1.f + __expf(-tot));
    }
}

// ---------------------------------------------------------------------------
// Workspace layout (bytes):
//   w_cat @ 0           : 4096*1536*2   = 12,582,912
//   bias  @ 12,582,912  : 4096*4        =     16,384
//   xbf   @ 12,599,296  : 256*256*512*2 = 67,108,864
//   hbuf0 @ 79,708,160  : 524,288
//   hbuf1 @ 80,232,448  : 524,288
//   bar   @ 80,756,736  : 2,048  (8 groups x 64 u32)
// ---------------------------------------------------------------------------
extern "C" void kernel_launch(void* const* d_in, const int* in_sizes, int n_in,
                              void* d_out, int out_size, void* d_ws, size_t ws_size,
                              hipStream_t stream) {
    const int*   text = (const int*)d_in[0];
    const float* emb  = (const float*)d_in[1];
    const float* w_ih = (const float*)d_in[2];
    const float* w_hh = (const float*)d_in[3];
    const float* b_ih = (const float*)d_in[4];
    const float* b_hh = (const float*)d_in[5];
    const float* fc_w = (const float*)d_in[6];
    const float* fc_b = (const float*)d_in[7];
    float* out = (float*)d_out;

    char* ws = (char*)d_ws;
    short* w_cat = (short*)(ws);
    float* bias  = (float*)(ws + 12582912);
    short* xbf   = (short*)(ws + 12599296);
    short* hbuf0 = (short*)(ws + 79708160);
    short* hbuf1 = (short*)(ws + 80232448);
    unsigned* bar = (unsigned*)(ws + 80756736);

    gather_kernel<<<dim3(BB * TT / 4), dim3(256), 0, stream>>>(text, emb, xbf);
    prep_kernel<<<dim3(G4), dim3(256), 0, stream>>>(w_ih, w_hh, b_ih, b_hh,
                                                    w_cat, bias, bar);

    const short* a0 = w_cat;
    const float* a1 = bias;
    const short* a2 = xbf;
    short*       a3 = hbuf0;
    short*       a4 = hbuf1;
    unsigned*    a5 = bar;
    void* args[] = { (void*)&a0, (void*)&a1, (void*)&a2,
                     (void*)&a3, (void*)&a4, (void*)&a5 };
    hipLaunchCooperativeKernel((const void*)lstm_seq, dim3(NBLK), dim3(256),
                               args, 0, stream);

    // After t=255 (odd), final h is in hbuf0
    fc_kernel<<<dim3(BB), dim3(256), 0, stream>>>(hbuf0, fc_w, fc_b, out);
}

// Round 7
// 4139.011 us; speedup vs baseline: 1.3285x; 1.3285x over previous
//
#include <hip/hip_runtime.h>

// Problem constants
#define TT 256
#define BB 256
#define EE 512
#define HH 1024
#define G4 4096
#define KTOT 1536
#define MB 32          // batch rows per block (8 groups of 32)
#define NBLK 512       // 64 j-tiles x 8 batch groups
#define BK 128         // K columns per staged chunk (round-2 proven value)
#define APAD 8

typedef __attribute__((ext_vector_type(8))) short short8;
typedef __attribute__((ext_vector_type(4))) float f32x4;

__device__ __forceinline__ short f2bf(float f) {
    unsigned u; __builtin_memcpy(&u, &f, 4);
    unsigned r = (u + 0x7FFFu + ((u >> 16) & 1u)) >> 16;   // RNE
    return (short)(unsigned short)r;
}
__device__ __forceinline__ float bf2f(short s) {
    unsigned u = ((unsigned)(unsigned short)s) << 16;
    float f; __builtin_memcpy(&f, &u, 4);
    return f;
}
__device__ __forceinline__ float sigf(float x) {
    return __builtin_amdgcn_rcpf(1.f + __expf(-x));
}
__device__ __forceinline__ float tanh_fast(float x) {
    return 2.f * sigf(x + x) - 1.f;
}

// Device-coherent 16-B h load: two agent-scope relaxed 8-B atomic loads
// (bypass possibly-stale L1/L2 -> fresh from L3). Proven in round 2.
__device__ __forceinline__ short8 ldh16(const short* p) {
    unsigned long long a = __hip_atomic_load((const unsigned long long*)p,
                                             __ATOMIC_RELAXED, __HIP_MEMORY_SCOPE_AGENT);
    unsigned long long b = __hip_atomic_load((const unsigned long long*)(p + 4),
                                             __ATOMIC_RELAXED, __HIP_MEMORY_SCOPE_AGENT);
    short8 v;
    __builtin_memcpy(&v, &a, 8);
    __builtin_memcpy((char*)&v + 8, &b, 8);
    return v;
}

// ---------------------------------------------------------------------------
// Prep: w_cat[r][0:1024]=w_hh[r], w_cat[r][1024:1536]=w_ih[r] (bf16);
//       bias[r] = b_ih[r] + b_hh[r]; block 0 zeroes barrier words.
// ---------------------------------------------------------------------------
__global__ __launch_bounds__(256) void prep_kernel(
    const float* __restrict__ w_ih, const float* __restrict__ w_hh,
    const float* __restrict__ b_ih, const float* __restrict__ b_hh,
    short* __restrict__ w_cat, float* __restrict__ bias,
    unsigned* __restrict__ bar)
{
    int r = blockIdx.x;
    int tid = threadIdx.x;
    for (int c = tid; c < KTOT; c += 256) {
        float v = (c < HH) ? w_hh[(size_t)r * HH + c]
                           : w_ih[(size_t)r * EE + (c - HH)];
        w_cat[(size_t)r * KTOT + c] = f2bf(v);
    }
    if (tid == 0) bias[r] = b_ih[r] + b_hh[r];
    if (r == 0) {
        for (int i = tid; i < 512; i += 256)
            __hip_atomic_store(bar + i, 0u, __ATOMIC_RELAXED, __HIP_MEMORY_SCOPE_AGENT);
    }
}

// ---------------------------------------------------------------------------
// Gather + convert: x_bf[t][b][:] = bf16(emb[text[b][t]][:])
// ---------------------------------------------------------------------------
__global__ __launch_bounds__(256) void gather_kernel(
    const int* __restrict__ text, const float* __restrict__ emb,
    short* __restrict__ xbf)
{
    int row = blockIdx.x * 4 + (threadIdx.x >> 6);   // b*TT + t
    int b = row >> 8, t = row & 255;
    int lane = threadIdx.x & 63;
    int v = text[row];
    const float* src = emb + (size_t)v * EE + lane * 8;
    float4 f0 = *(const float4*)src;
    float4 f1 = *(const float4*)(src + 4);
    float fv[8];
    *(float4*)&fv[0] = f0; *(float4*)&fv[4] = f1;
    short8 s;
    #pragma unroll
    for (int i = 0; i < 8; ++i) s[i] = f2bf(fv[i]);
    *(short8*)(xbf + ((size_t)t * BB + b) * EE + lane * 8) = s;
}

// ---------------------------------------------------------------------------
// Persistent LSTM, 512 blocks x 256 threads (2 blocks/CU).
// EXACT round-2 structure (verified pass @4092us, CK=128), with the single
// change: DEPTH-2 register prefetch in compute_x / compute_h. Loads for
// chunk c+2 are issued at iteration c (into the register set freed by the
// previous stage), giving each global/L3 load a full iteration (~mfma +
// barrier + mfma) of latency cover instead of one mfma_chunk.
// Same buffers, same __syncthreads protocol, same mapping, same numerics.
// ---------------------------------------------------------------------------
__global__ __launch_bounds__(256, 2) void lstm_seq(
    const short* __restrict__ w_cat,   // [4096][1536] bf16
    const float* __restrict__ bias,    // [4096]
    const short* __restrict__ xbf,     // [T][B][E] bf16
    short*       __restrict__ hbuf0,   // [B][H] bf16
    short*       __restrict__ hbuf1,   // [B][H] bf16
    unsigned*    __restrict__ bar)     // 8 groups x 64 u32 stride
{
    __shared__ short At[2][MB][BK + APAD];   // 2 x 32 x 136 bf16 = 17408 B
    __shared__ float Gt[4][MB][17];          // 8704 B

    const int tid  = threadIdx.x;
    const int wv   = tid >> 6;               // gate 0..3 (i,f,g,o)
    const int lane = tid & 63;
    const int n    = lane & 15;
    const int q    = lane >> 4;

    const int bid = blockIdx.x;
    const int xcd = bid & 7, sub = bid >> 3;   // sub 0..63
    const int jt  = xcd * 8 + (sub & 7);       // 0..63 j-tile (XCD-swizzled)
    const int g   = sub >> 3;                  // 0..7 batch group
    const int j0  = jt * 16;
    const int b0  = g * MB;

    unsigned* cnt = bar + g * 64;
    unsigned* gen = bar + g * 64 + 16;

    const short* wrow = w_cat + (size_t)(wv * HH + j0 + n) * KTOT;

    // A staging: thread -> (row ar, cols ac..ac+15) of the 32x128 chunk
    const int ar = tid >> 3;                 // 0..31
    const int ac = (tid & 7) * 16;           // 0,16,...,112
    const int ab = b0 + ar;
    const short* hrow0 = hbuf0 + (size_t)ab * HH + ac;
    const short* hrow1 = hbuf1 + (size_t)ab * HH + ac;
    const short* xbase = xbf + (size_t)ab * EE + ac;

    // Elementwise mapping: thread owns (batch eb, j jb..jb+1)
    const int m  = tid >> 3;
    const int n2 = (tid & 7) * 2;
    const int jb = j0 + n2;
    const int eb = b0 + m;
    float bi_[2], bf_[2], bg_[2], bo_[2];
    #pragma unroll
    for (int u = 0; u < 2; ++u) {
        bi_[u] = bias[jb + u];
        bf_[u] = bias[HH + jb + u];
        bg_[u] = bias[2 * HH + jb + u];
        bo_[u] = bias[3 * HH + jb + u];
    }
    float creg[2] = {0.f, 0.f};
    unsigned* hout_e = (unsigned*)(hbuf1 + (size_t)eb * HH + jb);  // even t
    unsigned* hout_o = (unsigned*)(hbuf0 + (size_t)eb * HH + jb);  // odd t

    f32x4 acc0, acc1;

    // --- helpers (round-2 idioms) ------------------------------------------
    auto stage2 = [&](int buf, short8 v0, short8 v1) {
        *(short8*)&At[buf][ar][ac]     = v0;
        *(short8*)&At[buf][ar][ac + 8] = v1;
    };
    auto mfma_chunk = [&](int buf, int k0) {      // one 128-col chunk
        #pragma unroll
        for (int ks = 0; ks < 4; ++ks) {
            short8 bfrag = *(const short8*)(wrow + k0 + ks * 32 + q * 8);
            short8 a0 = *(const short8*)&At[buf][n][ks * 32 + q * 8];
            short8 a1 = *(const short8*)&At[buf][16 + n][ks * 32 + q * 8];
            acc0 = __builtin_amdgcn_mfma_f32_16x16x32_bf16(a0, bfrag, acc0, 0, 0, 0);
            acc1 = __builtin_amdgcn_mfma_f32_16x16x32_bf16(a1, bfrag, acc1, 0, 0, 0);
        }
    };

    // x-part of step t's gates (K columns 1024..1536), 4 chunks, depth-2
    auto compute_x = [&](int t) {
        acc0 = (f32x4){0.f, 0.f, 0.f, 0.f};
        acc1 = (f32x4){0.f, 0.f, 0.f, 0.f};
        const short* xp = xbase + (size_t)t * (BB * EE);
        short8 pa0 = *(const short8*)(xp);           // chunk 0
        short8 pa1 = *(const short8*)(xp + 8);
        short8 pb0 = *(const short8*)(xp + BK);      // chunk 1
        short8 pb1 = *(const short8*)(xp + BK + 8);
        stage2(0, pa0, pa1);
        __syncthreads();
        // c=0: load chunk 2, compute chunk 0, stage chunk 1
        pa0 = *(const short8*)(xp + 2 * BK);
        pa1 = *(const short8*)(xp + 2 * BK + 8);
        mfma_chunk(0, HH);
        stage2(1, pb0, pb1);
        __syncthreads();
        // c=1: load chunk 3, compute chunk 1, stage chunk 2
        pb0 = *(const short8*)(xp + 3 * BK);
        pb1 = *(const short8*)(xp + 3 * BK + 8);
        mfma_chunk(1, HH + BK);
        stage2(0, pa0, pa1);
        __syncthreads();
        // c=2: compute chunk 2, stage chunk 3
        mfma_chunk(0, HH + 2 * BK);
        stage2(1, pb0, pb1);
        __syncthreads();
        // c=3: compute chunk 3
        mfma_chunk(1, HH + 3 * BK);
    };

    // h-part of step t's gates (K columns 0..1024), 8 chunks, depth-2
    auto compute_h = [&](int t) {
        const short* hp = (t & 1) ? hrow1 : hrow0;
        short8 pa0 = ldh16(hp);                      // chunk 0
        short8 pa1 = ldh16(hp + 8);
        short8 pb0 = ldh16(hp + BK);                 // chunk 1
        short8 pb1 = ldh16(hp + BK + 8);
        stage2(0, pa0, pa1);
        __syncthreads();
        // c=0
        pa0 = ldh16(hp + 2 * BK);  pa1 = ldh16(hp + 2 * BK + 8);
        mfma_chunk(0, 0);
        stage2(1, pb0, pb1);
        __syncthreads();
        // c=1
        pb0 = ldh16(hp + 3 * BK);  pb1 = ldh16(hp + 3 * BK + 8);
        mfma_chunk(1, BK);
        stage2(0, pa0, pa1);
        __syncthreads();
        // c=2
        pa0 = ldh16(hp + 4 * BK);  pa1 = ldh16(hp + 4 * BK + 8);
        mfma_chunk(0, 2 * BK);
        stage2(1, pb0, pb1);
        __syncthreads();
        // c=3
        pb0 = ldh16(hp + 5 * BK);  pb1 = ldh16(hp + 5 * BK + 8);
        mfma_chunk(1, 3 * BK);
        stage2(0, pa0, pa1);
        __syncthreads();
        // c=4
        pa0 = ldh16(hp + 6 * BK);  pa1 = ldh16(hp + 6 * BK + 8);
        mfma_chunk(0, 4 * BK);
        stage2(1, pb0, pb1);
        __syncthreads();
        // c=5
        pb0 = ldh16(hp + 7 * BK);  pb1 = ldh16(hp + 7 * BK + 8);
        mfma_chunk(1, 5 * BK);
        stage2(0, pa0, pa1);
        __syncthreads();
        // c=6
        mfma_chunk(0, 6 * BK);
        stage2(1, pb0, pb1);
        __syncthreads();
        // c=7
        mfma_chunk(1, 7 * BK);
    };
    // -----------------------------------------------------------------------

    compute_x(0);
    for (int t = 0; t < TT; ++t) {
        if (t > 0) {
            // wait for h(t-1): gen reaches t when all 64 group blocks arrived
            if (tid == 0) {
                while (__hip_atomic_load(gen, __ATOMIC_RELAXED, __HIP_MEMORY_SCOPE_AGENT)
                       < (unsigned)t)
                    __builtin_amdgcn_s_sleep(2);
            }
            __syncthreads();
            compute_h(t);
        }

        // Gate exchange through LDS
        #pragma unroll
        for (int r = 0; r < 4; ++r) {
            Gt[wv][q * 4 + r][n]      = acc0[r];
            Gt[wv][16 + q * 4 + r][n] = acc1[r];
        }
        __syncthreads();

        // Elementwise cell update (c in registers); coherent packed h store
        unsigned hw;
        {
            unsigned short hlo, hhi;
            #pragma unroll
            for (int u = 0; u < 2; ++u) {
                float ip = Gt[0][m][n2 + u] + bi_[u];
                float fp = Gt[1][m][n2 + u] + bf_[u];
                float gp = Gt[2][m][n2 + u] + bg_[u];
                float op = Gt[3][m][n2 + u] + bo_[u];
                float cn = sigf(fp) * creg[u] + sigf(ip) * tanh_fast(gp);
                creg[u]  = cn;
                unsigned short hb = (unsigned short)f2bf(sigf(op) * tanh_fast(cn));
                if (u == 0) hlo = hb; else hhi = hb;
            }
            hw = (unsigned)hlo | ((unsigned)hhi << 16);
        }
        __hip_atomic_store((t & 1) ? hout_o : hout_e, hw,
                           __ATOMIC_RELAXED, __HIP_MEMORY_SCOPE_AGENT);

        if (t + 1 < TT) {
            __syncthreads();   // all h stores drained (vmcnt) before arrival
            if (tid == 0) {
                unsigned a = __hip_atomic_fetch_add(cnt, 1u, __ATOMIC_RELAXED,
                                                    __HIP_MEMORY_SCOPE_AGENT);
                if (a == 63u) {
                    __hip_atomic_store(cnt, 0u, __ATOMIC_RELAXED,
                                       __HIP_MEMORY_SCOPE_AGENT);
                    __hip_atomic_fetch_add(gen, 1u, __ATOMIC_RELEASE,
                                           __HIP_MEMORY_SCOPE_AGENT);
                }
            }
            compute_x(t + 1);  // hide barrier resolution behind x-part GEMM
        }
    }
}

// ---------------------------------------------------------------------------
// FC head: out[b] = sigmoid(dot(h[b], fc_w) + fc_b)
// ---------------------------------------------------------------------------
__global__ __launch_bounds__(256) void fc_kernel(
    const short* __restrict__ hbuf, const float* __restrict__ fc_w,
    const float* __restrict__ fc_b, float* __restrict__ out)
{
    __shared__ float red[4];
    int b = blockIdx.x;
    int tid = threadIdx.x;
    float s = 0.f;
    for (int k = tid; k < HH; k += 256)
        s += bf2f(hbuf[(size_t)b * HH + k]) * fc_w[k];
    #pragma unroll
    for (int off = 32; off > 0; off >>= 1) s += __shfl_down(s, off);
    if ((tid & 63) == 0) red[tid >> 6] = s;
    __syncthreads();
    if (tid == 0) {
        float tot = red[0] + red[1] + red[2] + red[3] + fc_b[0];
        out[b] = 1.f / (1.f + __expf(-tot));
    }
}

// ---------------------------------------------------------------------------
// Workspace layout (bytes):
//   w_cat @ 0           : 4096*1536*2   = 12,582,912
//   bias  @ 12,582,912  : 4096*4        =     16,384
//   xbf   @ 12,599,296  : 256*256*512*2 = 67,108,864
//   hbuf0 @ 79,708,160  : 524,288
//   hbuf1 @ 80,232,448  : 524,288
//   bar   @ 80,756,736  : 2,048  (8 groups x 64 u32)
// ---------------------------------------------------------------------------
extern "C" void kernel_launch(void* const* d_in, const int* in_sizes, int n_in,
                              void* d_out, int out_size, void* d_ws, size_t ws_size,
                              hipStream_t stream) {
    const int*   text = (const int*)d_in[0];
    const float* emb  = (const float*)d_in[1];
    const float* w_ih = (const float*)d_in[2];
    const float* w_hh = (const float*)d_in[3];
    const float* b_ih = (const float*)d_in[4];
    const float* b_hh = (const float*)d_in[5];
    const float* fc_w = (const float*)d_in[6];
    const float* fc_b = (const float*)d_in[7];
    float* out = (float*)d_out;

    char* ws = (char*)d_ws;
    short* w_cat = (short*)(ws);
    float* bias  = (float*)(ws + 12582912);
    short* xbf   = (short*)(ws + 12599296);
    short* hbuf0 = (short*)(ws + 79708160);
    short* hbuf1 = (short*)(ws + 80232448);
    unsigned* bar = (unsigned*)(ws + 80756736);

    gather_kernel<<<dim3(BB * TT / 4), dim3(256), 0, stream>>>(text, emb, xbf);
    prep_kernel<<<dim3(G4), dim3(256), 0, stream>>>(w_ih, w_hh, b_ih, b_hh,
                                                    w_cat, bias, bar);

    const short* a0 = w_cat;
    const float* a1 = bias;
    const short* a2 = xbf;
    short*       a3 = hbuf0;
    short*       a4 = hbuf1;
    unsigned*    a5 = bar;
    void* args[] = { (void*)&a0, (void*)&a1, (void*)&a2,
                     (void*)&a3, (void*)&a4, (void*)&a5 };
    hipLaunchCooperativeKernel((const void*)lstm_seq, dim3(NBLK), dim3(256),
                               args, 0, stream);

    // After t=255 (odd), final h is in hbuf0
    fc_kernel<<<dim3(BB), dim3(256), 0, stream>>>(hbuf0, fc_w, fc_b, out);
}

// Round 8
// 4083.881 us; speedup vs baseline: 1.3464x; 1.0135x over previous
//
#include <hip/hip_runtime.h>

// Problem constants
#define TT 256
#define BB 256
#define EE 512
#define HH 1024
#define G4 4096
#define KTOT 1536
#define MB 32          // batch rows per block (8 groups of 32)
#define NBLK 512       // 64 j-tiles x 8 batch groups
#define BK 128         // K columns per staged chunk (round-2 proven value)
#define APAD 8

typedef __attribute__((ext_vector_type(8))) short short8;
typedef __attribute__((ext_vector_type(4))) float f32x4;

__device__ __forceinline__ short f2bf(float f) {
    unsigned u; __builtin_memcpy(&u, &f, 4);
    unsigned r = (u + 0x7FFFu + ((u >> 16) & 1u)) >> 16;   // RNE
    return (short)(unsigned short)r;
}
__device__ __forceinline__ float bf2f(short s) {
    unsigned u = ((unsigned)(unsigned short)s) << 16;
    float f; __builtin_memcpy(&f, &u, 4);
    return f;
}
__device__ __forceinline__ float sigf(float x) {
    return __builtin_amdgcn_rcpf(1.f + __expf(-x));
}
__device__ __forceinline__ float tanh_fast(float x) {
    return 2.f * sigf(x + x) - 1.f;
}

// Device-coherent 16-B h load: two agent-scope relaxed 8-B atomic loads
// (bypass possibly-stale L1/L2 -> fresh from L3). Proven in round 2.
__device__ __forceinline__ short8 ldh16(const short* p) {
    unsigned long long a = __hip_atomic_load((const unsigned long long*)p,
                                             __ATOMIC_RELAXED, __HIP_MEMORY_SCOPE_AGENT);
    unsigned long long b = __hip_atomic_load((const unsigned long long*)(p + 4),
                                             __ATOMIC_RELAXED, __HIP_MEMORY_SCOPE_AGENT);
    short8 v;
    __builtin_memcpy(&v, &a, 8);
    __builtin_memcpy((char*)&v + 8, &b, 8);
    return v;
}

// K-loop barrier: publishes LDS writes (lgkmcnt(0)) WITHOUT draining vmcnt,
// so global/L3 prefetch loads stay in flight across it. The compiler still
// emits counted s_waitcnt vmcnt(N) before each ds_write that consumes a
// loaded register (dependency-tracked) -- implicit T4 counted-vmcnt.
// All LDS accesses are compiler-visible loads/stores (no asm ds ops).
#define RBAR() do {                                            \
    asm volatile("s_waitcnt lgkmcnt(0)" ::: "memory");         \
    __builtin_amdgcn_s_barrier();                              \
} while (0)

// ---------------------------------------------------------------------------
// Prep: w_cat[r][0:1024]=w_hh[r], w_cat[r][1024:1536]=w_ih[r] (bf16);
//       bias[r] = b_ih[r] + b_hh[r]; block 0 zeroes barrier words.
// ---------------------------------------------------------------------------
__global__ __launch_bounds__(256) void prep_kernel(
    const float* __restrict__ w_ih, const float* __restrict__ w_hh,
    const float* __restrict__ b_ih, const float* __restrict__ b_hh,
    short* __restrict__ w_cat, float* __restrict__ bias,
    unsigned* __restrict__ bar)
{
    int r = blockIdx.x;
    int tid = threadIdx.x;
    for (int c = tid; c < KTOT; c += 256) {
        float v = (c < HH) ? w_hh[(size_t)r * HH + c]
                           : w_ih[(size_t)r * EE + (c - HH)];
        w_cat[(size_t)r * KTOT + c] = f2bf(v);
    }
    if (tid == 0) bias[r] = b_ih[r] + b_hh[r];
    if (r == 0) {
        for (int i = tid; i < 512; i += 256)
            __hip_atomic_store(bar + i, 0u, __ATOMIC_RELAXED, __HIP_MEMORY_SCOPE_AGENT);
    }
}

// ---------------------------------------------------------------------------
// Gather + convert: x_bf[t][b][:] = bf16(emb[text[b][t]][:])
// ---------------------------------------------------------------------------
__global__ __launch_bounds__(256) void gather_kernel(
    const int* __restrict__ text, const float* __restrict__ emb,
    short* __restrict__ xbf)
{
    int row = blockIdx.x * 4 + (threadIdx.x >> 6);   // b*TT + t
    int b = row >> 8, t = row & 255;
    int lane = threadIdx.x & 63;
    int v = text[row];
    const float* src = emb + (size_t)v * EE + lane * 8;
    float4 f0 = *(const float4*)src;
    float4 f1 = *(const float4*)(src + 4);
    float fv[8];
    *(float4*)&fv[0] = f0; *(float4*)&fv[4] = f1;
    short8 s;
    #pragma unroll
    for (int i = 0; i < 8; ++i) s[i] = f2bf(fv[i]);
    *(short8*)(xbf + ((size_t)t * BB + b) * EE + lane * 8) = s;
}

// ---------------------------------------------------------------------------
// Persistent LSTM, 512 blocks x 256 threads (2 blocks/CU).
// Round-7 structure (= round-2 proven mapping + depth-2 register prefetch),
// with the SINGLE isolated change: all K-loop intra-step barriers are
// lgkmcnt-only RBAR() instead of __syncthreads(), so prefetched global/L3
// loads survive across barriers. __syncthreads() remains at the two
// store/acquire-critical points: post-spin (h acquire) and post-h-store
// (drain before group-barrier arrival).
// ---------------------------------------------------------------------------
__global__ __launch_bounds__(256, 2) void lstm_seq(
    const short* __restrict__ w_cat,   // [4096][1536] bf16
    const float* __restrict__ bias,    // [4096]
    const short* __restrict__ xbf,     // [T][B][E] bf16
    short*       __restrict__ hbuf0,   // [B][H] bf16
    short*       __restrict__ hbuf1,   // [B][H] bf16
    unsigned*    __restrict__ bar)     // 8 groups x 64 u32 stride
{
    __shared__ short At[2][MB][BK + APAD];   // 2 x 32 x 136 bf16 = 17408 B
    __shared__ float Gt[4][MB][17];          // 8704 B

    const int tid  = threadIdx.x;
    const int wv   = tid >> 6;               // gate 0..3 (i,f,g,o)
    const int lane = tid & 63;
    const int n    = lane & 15;
    const int q    = lane >> 4;

    const int bid = blockIdx.x;
    const int xcd = bid & 7, sub = bid >> 3;   // sub 0..63
    const int jt  = xcd * 8 + (sub & 7);       // 0..63 j-tile (XCD-swizzled)
    const int g   = sub >> 3;                  // 0..7 batch group
    const int j0  = jt * 16;
    const int b0  = g * MB;

    unsigned* cnt = bar + g * 64;
    unsigned* gen = bar + g * 64 + 16;

    const short* wrow = w_cat + (size_t)(wv * HH + j0 + n) * KTOT;

    // A staging: thread -> (row ar, cols ac..ac+15) of the 32x128 chunk
    const int ar = tid >> 3;                 // 0..31
    const int ac = (tid & 7) * 16;           // 0,16,...,112
    const int ab = b0 + ar;
    const short* hrow0 = hbuf0 + (size_t)ab * HH + ac;
    const short* hrow1 = hbuf1 + (size_t)ab * HH + ac;
    const short* xbase = xbf + (size_t)ab * EE + ac;

    // Elementwise mapping: thread owns (batch eb, j jb..jb+1)
    const int m  = tid >> 3;
    const int n2 = (tid & 7) * 2;
    const int jb = j0 + n2;
    const int eb = b0 + m;
    float bi_[2], bf_[2], bg_[2], bo_[2];
    #pragma unroll
    for (int u = 0; u < 2; ++u) {
        bi_[u] = bias[jb + u];
        bf_[u] = bias[HH + jb + u];
        bg_[u] = bias[2 * HH + jb + u];
        bo_[u] = bias[3 * HH + jb + u];
    }
    float creg[2] = {0.f, 0.f};
    unsigned* hout_e = (unsigned*)(hbuf1 + (size_t)eb * HH + jb);  // even t
    unsigned* hout_o = (unsigned*)(hbuf0 + (size_t)eb * HH + jb);  // odd t

    f32x4 acc0, acc1;

    // --- helpers (round-2 idioms) ------------------------------------------
    auto stage2 = [&](int buf, short8 v0, short8 v1) {
        *(short8*)&At[buf][ar][ac]     = v0;
        *(short8*)&At[buf][ar][ac + 8] = v1;
    };
    auto mfma_chunk = [&](int buf, int k0) {      // one 128-col chunk
        #pragma unroll
        for (int ks = 0; ks < 4; ++ks) {
            short8 bfrag = *(const short8*)(wrow + k0 + ks * 32 + q * 8);
            short8 a0 = *(const short8*)&At[buf][n][ks * 32 + q * 8];
            short8 a1 = *(const short8*)&At[buf][16 + n][ks * 32 + q * 8];
            acc0 = __builtin_amdgcn_mfma_f32_16x16x32_bf16(a0, bfrag, acc0, 0, 0, 0);
            acc1 = __builtin_amdgcn_mfma_f32_16x16x32_bf16(a1, bfrag, acc1, 0, 0, 0);
        }
    };

    // x-part of step t's gates (K columns 1024..1536), 4 chunks, depth-2
    auto compute_x = [&](int t) {
        acc0 = (f32x4){0.f, 0.f, 0.f, 0.f};
        acc1 = (f32x4){0.f, 0.f, 0.f, 0.f};
        const short* xp = xbase + (size_t)t * (BB * EE);
        short8 pa0 = *(const short8*)(xp);           // chunk 0
        short8 pa1 = *(const short8*)(xp + 8);
        short8 pb0 = *(const short8*)(xp + BK);      // chunk 1
        short8 pb1 = *(const short8*)(xp + BK + 8);
        stage2(0, pa0, pa1);
        RBAR();
        // c=0: load chunk 2, compute chunk 0, stage chunk 1
        pa0 = *(const short8*)(xp + 2 * BK);
        pa1 = *(const short8*)(xp + 2 * BK + 8);
        mfma_chunk(0, HH);
        stage2(1, pb0, pb1);
        RBAR();
        // c=1: load chunk 3, compute chunk 1, stage chunk 2
        pb0 = *(const short8*)(xp + 3 * BK);
        pb1 = *(const short8*)(xp + 3 * BK + 8);
        mfma_chunk(1, HH + BK);
        stage2(0, pa0, pa1);
        RBAR();
        // c=2: compute chunk 2, stage chunk 3
        mfma_chunk(0, HH + 2 * BK);
        stage2(1, pb0, pb1);
        RBAR();
        // c=3: compute chunk 3
        mfma_chunk(1, HH + 3 * BK);
    };

    // h-part of step t's gates (K columns 0..1024), 8 chunks, depth-2
    auto compute_h = [&](int t) {
        const short* hp = (t & 1) ? hrow1 : hrow0;
        short8 pa0 = ldh16(hp);                      // chunk 0
        short8 pa1 = ldh16(hp + 8);
        short8 pb0 = ldh16(hp + BK);                 // chunk 1
        short8 pb1 = ldh16(hp + BK + 8);
        stage2(0, pa0, pa1);
        RBAR();
        // c=0
        pa0 = ldh16(hp + 2 * BK);  pa1 = ldh16(hp + 2 * BK + 8);
        mfma_chunk(0, 0);
        stage2(1, pb0, pb1);
        RBAR();
        // c=1
        pb0 = ldh16(hp + 3 * BK);  pb1 = ldh16(hp + 3 * BK + 8);
        mfma_chunk(1, BK);
        stage2(0, pa0, pa1);
        RBAR();
        // c=2
        pa0 = ldh16(hp + 4 * BK);  pa1 = ldh16(hp + 4 * BK + 8);
        mfma_chunk(0, 2 * BK);
        stage2(1, pb0, pb1);
        RBAR();
        // c=3
        pb0 = ldh16(hp + 5 * BK);  pb1 = ldh16(hp + 5 * BK + 8);
        mfma_chunk(1, 3 * BK);
        stage2(0, pa0, pa1);
        RBAR();
        // c=4
        pa0 = ldh16(hp + 6 * BK);  pa1 = ldh16(hp + 6 * BK + 8);
        mfma_chunk(0, 4 * BK);
        stage2(1, pb0, pb1);
        RBAR();
        // c=5
        pb0 = ldh16(hp + 7 * BK);  pb1 = ldh16(hp + 7 * BK + 8);
        mfma_chunk(1, 5 * BK);
        stage2(0, pa0, pa1);
        RBAR();
        // c=6
        mfma_chunk(0, 6 * BK);
        stage2(1, pb0, pb1);
        RBAR();
        // c=7
        mfma_chunk(1, 7 * BK);
    };
    // -----------------------------------------------------------------------

    compute_x(0);
    for (int t = 0; t < TT; ++t) {
        if (t > 0) {
            // wait for h(t-1): gen reaches t when all 64 group blocks arrived
            if (tid == 0) {
                while (__hip_atomic_load(gen, __ATOMIC_RELAXED, __HIP_MEMORY_SCOPE_AGENT)
                       < (unsigned)t)
                    __builtin_amdgcn_s_sleep(2);
            }
            __syncthreads();   // acquire: release all waves to load h(t-1)
            compute_h(t);
        }

        // Gate exchange through LDS
        #pragma unroll
        for (int r = 0; r < 4; ++r) {
            Gt[wv][q * 4 + r][n]      = acc0[r];
            Gt[wv][16 + q * 4 + r][n] = acc1[r];
        }
        RBAR();

        // Elementwise cell update (c in registers); coherent packed h store
        unsigned hw;
        {
            unsigned short hlo, hhi;
            #pragma unroll
            for (int u = 0; u < 2; ++u) {
                float ip = Gt[0][m][n2 + u] + bi_[u];
                float fp = Gt[1][m][n2 + u] + bf_[u];
                float gp = Gt[2][m][n2 + u] + bg_[u];
                float op = Gt[3][m][n2 + u] + bo_[u];
                float cn = sigf(fp) * creg[u] + sigf(ip) * tanh_fast(gp);
                creg[u]  = cn;
                unsigned short hb = (unsigned short)f2bf(sigf(op) * tanh_fast(cn));
                if (u == 0) hlo = hb; else hhi = hb;
            }
            hw = (unsigned)hlo | ((unsigned)hhi << 16);
        }
        __hip_atomic_store((t & 1) ? hout_o : hout_e, hw,
                           __ATOMIC_RELAXED, __HIP_MEMORY_SCOPE_AGENT);

        if (t + 1 < TT) {
            __syncthreads();   // FULL sync: h stores drained before arrival
            if (tid == 0) {
                unsigned a = __hip_atomic_fetch_add(cnt, 1u, __ATOMIC_RELAXED,
                                                    __HIP_MEMORY_SCOPE_AGENT);
                if (a == 63u) {
                    __hip_atomic_store(cnt, 0u, __ATOMIC_RELAXED,
                                       __HIP_MEMORY_SCOPE_AGENT);
                    __hip_atomic_fetch_add(gen, 1u, __ATOMIC_RELEASE,
                                           __HIP_MEMORY_SCOPE_AGENT);
                }
            }
            compute_x(t + 1);  // hide barrier resolution behind x-part GEMM
        }
    }
}

// ---------------------------------------------------------------------------
// FC head: out[b] = sigmoid(dot(h[b], fc_w) + fc_b)
// ---------------------------------------------------------------------------
__global__ __launch_bounds__(256) void fc_kernel(
    const short* __restrict__ hbuf, const float* __restrict__ fc_w,
    const float* __restrict__ fc_b, float* __restrict__ out)
{
    __shared__ float red[4];
    int b = blockIdx.x;
    int tid = threadIdx.x;
    float s = 0.f;
    for (int k = tid; k < HH; k += 256)
        s += bf2f(hbuf[(size_t)b * HH + k]) * fc_w[k];
    #pragma unroll
    for (int off = 32; off > 0; off >>= 1) s += __shfl_down(s, off);
    if ((tid & 63) == 0) red[tid >> 6] = s;
    __syncthreads();
    if (tid == 0) {
        float tot = red[0] + red[1] + red[2] + red[3] + fc_b[0];
        out[b] = 1.f / (1.f + __expf(-tot));
    }
}

// ---------------------------------------------------------------------------
// Workspace layout (bytes):
//   w_cat @ 0           : 4096*1536*2   = 12,582,912
//   bias  @ 12,582,912  : 4096*4        =     16,384
//   xbf   @ 12,599,296  : 256*256*512*2 = 67,108,864
//   hbuf0 @ 79,708,160  : 524,288
//   hbuf1 @ 80,232,448  : 524,288
//   bar   @ 80,756,736  : 2,048  (8 groups x 64 u32)
// ---------------------------------------------------------------------------
extern "C" void kernel_launch(void* const* d_in, const int* in_sizes, int n_in,
                              void* d_out, int out_size, void* d_ws, size_t ws_size,
                              hipStream_t stream) {
    const int*   text = (const int*)d_in[0];
    const float* emb  = (const float*)d_in[1];
    const float* w_ih = (const float*)d_in[2];
    const float* w_hh = (const float*)d_in[3];
    const float* b_ih = (const float*)d_in[4];
    const float* b_hh = (const float*)d_in[5];
    const float* fc_w = (const float*)d_in[6];
    const float* fc_b = (const float*)d_in[7];
    float* out = (float*)d_out;

    char* ws = (char*)d_ws;
    short* w_cat = (short*)(ws);
    float* bias  = (float*)(ws + 12582912);
    short* xbf   = (short*)(ws + 12599296);
    short* hbuf0 = (short*)(ws + 79708160);
    short* hbuf1 = (short*)(ws + 80232448);
    unsigned* bar = (unsigned*)(ws + 80756736);

    gather_kernel<<<dim3(BB * TT / 4), dim3(256), 0, stream>>>(text, emb, xbf);
    prep_kernel<<<dim3(G4), dim3(256), 0, stream>>>(w_ih, w_hh, b_ih, b_hh,
                                                    w_cat, bias, bar);

    const short* a0 = w_cat;
    const float* a1 = bias;
    const short* a2 = xbf;
    short*       a3 = hbuf0;
    short*       a4 = hbuf1;
    unsigned*    a5 = bar;
    void* args[] = { (void*)&a0, (void*)&a1, (void*)&a2,
                     (void*)&a3, (void*)&a4, (void*)&a5 };
    hipLaunchCooperativeKernel((const void*)lstm_seq, dim3(NBLK), dim3(256),
                               args, 0, stream);

    // After t=255 (odd), final h is in hbuf0
    fc_kernel<<<dim3(BB), dim3(256), 0, stream>>>(hbuf0, fc_w, fc_b, out);
}